// Round 3
// baseline (255.221 us; speedup 1.0000x reference)
//
#include <hip/hip_runtime.h>
#include <hip/hip_bf16.h>

#define N 4096
#define F 256
#define P 5
#define EPSV 1e-8f
#define BK 32
#define NSTEP (F / BK)  // 8

typedef __attribute__((ext_vector_type(8))) short bf16x8;
typedef __attribute__((ext_vector_type(4))) float f32x4;

__device__ __forceinline__ f32x4 mfma16(bf16x8 a, bf16x8 b, f32x4 c) {
    return __builtin_amdgcn_mfma_f32_16x16x32_bf16(a, b, c, 0, 0, 0);
}

__device__ __forceinline__ void gload16(const __hip_bfloat16* src, const char* ldsdst) {
    __builtin_amdgcn_global_load_lds(
        (const __attribute__((address_space(1))) void*)src,
        (__attribute__((address_space(3))) void*)ldsdst, 16, 0, 0);
}

// K0 (fused): msg = E @ A via sparse index compaction, norms, bf16 casts,
// per-(persona,row) float4 param table {alpha, beta, p, p+delta}, per-persona consts.
__global__ __launch_bounds__(256, 8) void prep_kernel(
    const float* __restrict__ E, const float* __restrict__ A,
    const float* __restrict__ persona,
    const float* __restrict__ Tt, const float* __restrict__ ee,
    const float* __restrict__ rr, const float* __restrict__ Ww,
    const int* __restrict__ times,
    __hip_bfloat16* __restrict__ Abf, __hip_bfloat16* __restrict__ Mbf,
    float4* __restrict__ qtab, float* __restrict__ cst) {
    __shared__ int cnt;
    __shared__ int list[1024];
    const int a = blockIdx.x;
    const int t = threadIdx.x;
    if (t == 0) cnt = 0;
    __syncthreads();
    const float4* erow = (const float4*)(E + (size_t)a * N);
    for (int b = t; b < N / 4; b += 256) {
        const float4 v = erow[b];
        if (v.x != 0.f) list[atomicAdd(&cnt, 1)] = 4 * b;
        if (v.y != 0.f) list[atomicAdd(&cnt, 1)] = 4 * b + 1;
        if (v.z != 0.f) list[atomicAdd(&cnt, 1)] = 4 * b + 2;
        if (v.w != 0.f) list[atomicAdd(&cnt, 1)] = 4 * b + 3;
    }
    __syncthreads();
    const int c = cnt;
    float s0 = 0.f, s1 = 0.f, s2 = 0.f, s3 = 0.f;
    int j = 0;
    for (; j + 4 <= c; j += 4) {
        s0 += A[(size_t)list[j] * F + t];
        s1 += A[(size_t)list[j + 1] * F + t];
        s2 += A[(size_t)list[j + 2] * F + t];
        s3 += A[(size_t)list[j + 3] * F + t];
    }
    for (; j < c; ++j) s0 += A[(size_t)list[j] * F + t];
    const float mv = (s0 + s1) + (s2 + s3);
    const float av = A[(size_t)a * F + t];
    Abf[(size_t)a * F + t] = __float2bfloat16(av);
    Mbf[(size_t)a * F + t] = __float2bfloat16(mv);

    float paa = av * av, pam = av * mv, pmm = mv * mv;
    #pragma unroll
    for (int o = 32; o > 0; o >>= 1) {
        paa += __shfl_down(paa, o);
        pam += __shfl_down(pam, o);
        pmm += __shfl_down(pmm, o);
    }
    __shared__ float s[3][4];
    const int wid = t >> 6;
    if ((t & 63) == 0) { s[0][wid] = paa; s[1][wid] = pam; s[2][wid] = pmm; }
    __syncthreads();
    if (t < P) {
        const float naa = s[0][0] + s[0][1] + s[0][2] + s[0][3];
        const float nam = s[1][0] + s[1][1] + s[1][2] + s[1][3];
        const float nmm = s[2][0] + s[2][1] + s[2][2] + s[2][3];
        const float Ti = Tt[t], ei = ee[t], ri = rr[t], Wi = Ww[t];
        const float wb = (1.f - ri) * Wi;
        const float n2 = ri * ri * naa + 2.f * ri * wb * nam + wb * wb * nmm;
        const float rn = rsqrtf(n2);
        const float p = persona[(size_t)(*times) * (size_t)N * P + (size_t)a * P + t];
        float4 q;
        q.x = ri * rn;                       // alpha
        q.y = wb * rn;                       // beta
        q.z = p;                             // p0
        q.w = p + (t == 0 ? 1.f : 0.f);      // p1 (i==0 init term)
        qtab[t * N + a] = q;
        if (a == 0) {
            // x = sc * exp(g*invT) with sc = e/(e*exp(invT)+EPS)  [max g == 1 analytic]
            const float invT = 1.f / (Ti + EPSV);
            const float sc = ei / (ei * __expf(invT) + EPSV);
            cst[2 * t] = invT * 1.4426950408889634f;   // k1 (log2 exponent scale)
            cst[2 * t + 1] = __log2f(sc);              // lsc (folded post-scale)
        }
    }
}

// K1: fused 4-Gram MFMA + dual-tile persona epilogue over the upper triangle.
// 64x64 tile, 4 waves (2x2), global_load_lds double-buffered staging, swizzled LDS.
__global__ __launch_bounds__(256, 4) void gram_kernel(
    const __hip_bfloat16* __restrict__ Abf, const __hip_bfloat16* __restrict__ Mbf,
    const float4* __restrict__ qtab, const float* __restrict__ cst,
    float* __restrict__ out) {
    // 2 buffers x 4 panels (rowA,rowM,colA,colM) x [64][32] bf16 = 32 KB; reused for transpose.
    __shared__ __align__(16) char smem[32768];

    const int t = threadIdx.x;
    const int lane = t & 63;
    const int w = t >> 6;
    const int wr = w >> 1, wc = w & 1;

    // triangle decode: bid -> (by <= bx)
    int bid = blockIdx.x;
    int bx = (int)((sqrtf(8.f * (float)bid + 1.f) - 1.f) * 0.5f);
    while ((bx + 1) * (bx + 2) / 2 <= bid) ++bx;
    while (bx * (bx + 1) / 2 > bid) --bx;
    const int by = bid - bx * (bx + 1) / 2;
    const int row0 = by << 6, col0 = bx << 6;

    // staging: wave w stages rows [w*16, w*16+16) of each panel, 16B/lane,
    // source column pre-swizzled (involution: slot ^ ((row>>1)&3)); LDS stays linear.
    const int srow = lane >> 2;
    const int sslot = (lane & 3) ^ ((lane >> 3) & 3);
    const size_t rbase = (size_t)row0 * F;
    const size_t cbase = (size_t)col0 * F;
    const size_t soff = (size_t)(w * 16 + srow) * F + (sslot << 3);

    #define STAGE(b, ks)  do {                                            \
        const char* lb = smem + (b) * 16384 + w * 1024;                   \
        gload16(Abf + rbase + soff + (ks), lb);                           \
        gload16(Mbf + rbase + soff + (ks), lb + 4096);                    \
        gload16(Abf + cbase + soff + (ks), lb + 8192);                    \
        gload16(Mbf + cbase + soff + (ks), lb + 12288);                   \
    } while (0)

    const int frow = lane & 15;
    const int rdslot = ((lane >> 4) ^ ((frow >> 1) & 3)) << 4;

    f32x4 acc[4][2][2];
    #pragma unroll
    for (int g = 0; g < 4; ++g)
        #pragma unroll
        for (int m = 0; m < 2; ++m)
            #pragma unroll
            for (int n = 0; n < 2; ++n) acc[g][m][n] = (f32x4){0.f, 0.f, 0.f, 0.f};

    STAGE(0, 0);
    __syncthreads();
    for (int s = 0; s < NSTEP; ++s) {
        const int b = s & 1;
        if (s + 1 < NSTEP) STAGE(b ^ 1, (s + 1) * BK);
        const char* base = smem + b * 16384;
        bf16x8 aA[2], aM[2], bA[2], bM[2];
        #pragma unroll
        for (int m = 0; m < 2; ++m) {
            const int ro = (wr * 32 + m * 16 + frow) * 64 + rdslot;
            aA[m] = *(const bf16x8*)(base + ro);
            aM[m] = *(const bf16x8*)(base + 4096 + ro);
        }
        #pragma unroll
        for (int n = 0; n < 2; ++n) {
            const int co = (wc * 32 + n * 16 + frow) * 64 + rdslot;
            bA[n] = *(const bf16x8*)(base + 8192 + co);
            bM[n] = *(const bf16x8*)(base + 12288 + co);
        }
        #pragma unroll
        for (int m = 0; m < 2; ++m)
            #pragma unroll
            for (int n = 0; n < 2; ++n) {
                acc[0][m][n] = mfma16(aA[m], bA[n], acc[0][m][n]);
                acc[1][m][n] = mfma16(aA[m], bM[n], acc[1][m][n]);
                acc[2][m][n] = mfma16(aM[m], bA[n], acc[2][m][n]);
                acc[3][m][n] = mfma16(aM[m], bM[n], acc[3][m][n]);
            }
        __syncthreads();
    }

    // Epilogue: g symmetric; out(r,c) = sum th*pc0*pr1, out(c,r) = sum th*pr0*pc1
    const int jr = (lane >> 4) << 2;
    float o1[2][2][4], o2[2][2][4];
    #pragma unroll
    for (int m = 0; m < 2; ++m)
        #pragma unroll
        for (int n = 0; n < 2; ++n)
            #pragma unroll
            for (int j = 0; j < 4; ++j) { o1[m][n][j] = 0.f; o2[m][n][j] = 0.f; }

    #pragma unroll
    for (int i = 0; i < P; ++i) {
        const float k1 = cst[2 * i], lsc = cst[2 * i + 1];
        float4 qc[2];
        #pragma unroll
        for (int n = 0; n < 2; ++n)
            qc[n] = qtab[i * N + col0 + wc * 32 + n * 16 + (lane & 15)];
        #pragma unroll
        for (int m = 0; m < 2; ++m) {
            #pragma unroll
            for (int j = 0; j < 4; ++j) {
                const int gr = row0 + wr * 32 + m * 16 + jr + j;
                const float4 qr = qtab[i * N + gr];
                #pragma unroll
                for (int n = 0; n < 2; ++n) {
                    const float h0 = qr.x * acc[0][m][n][j] + qr.y * acc[2][m][n][j];
                    const float h1 = qr.x * acc[1][m][n][j] + qr.y * acc[3][m][n][j];
                    const float g = h0 * qc[n].x + h1 * qc[n].y;
                    const float x = exp2f(fmaf(g, k1, lsc));
                    const float e2 = exp2f(x * 2.8853900817779268f);  // exp(2x)
                    const float th = 1.f - 2.f * __builtin_amdgcn_rcpf(e2 + 1.f);
                    o1[m][n][j] = fmaf(th * qc[n].z, qr.w, o1[m][n][j]);
                    o2[m][n][j] = fmaf(th * qr.z, qc[n].w, o2[m][n][j]);
                }
            }
        }
    }

    // tile1 (row0, col0): direct coalesced stores
    #pragma unroll
    for (int m = 0; m < 2; ++m)
        #pragma unroll
        for (int j = 0; j < 4; ++j) {
            const int gr = row0 + wr * 32 + m * 16 + jr + j;
            #pragma unroll
            for (int n = 0; n < 2; ++n) {
                const int gc = col0 + wc * 32 + n * 16 + (lane & 15);
                out[(size_t)gr * N + gc] = o1[m][n][j];
            }
        }

    // tile2 (col0, row0): transpose through LDS (XOR-swizzled f32 [64][64]), float4 stores
    if (by != bx) {
        float* tb = (float*)smem;
        #pragma unroll
        for (int m = 0; m < 2; ++m)
            #pragma unroll
            for (int n = 0; n < 2; ++n) {
                const int lc = wc * 32 + n * 16 + (lane & 15);
                #pragma unroll
                for (int j = 0; j < 4; ++j) {
                    const int lr = wr * 32 + m * 16 + jr + j;
                    tb[lc * 64 + (lr ^ ((lc & 15) << 2))] = o2[m][n][j];
                }
            }
        __syncthreads();
        const int trow = t >> 2;
        const int tc4 = (t & 3) << 2;
        #pragma unroll
        for (int k = 0; k < 4; ++k) {
            const int col = (tc4 + k * 16) ^ ((trow & 15) << 2);
            const float4 v = *(const float4*)&tb[trow * 64 + col];
            *(float4*)&out[(size_t)(col0 + trow) * N + row0 + tc4 + k * 16] = v;
        }
    }
    #undef STAGE
}

extern "C" void kernel_launch(void* const* d_in, const int* in_sizes, int n_in,
                              void* d_out, int out_size, void* d_ws, size_t ws_size,
                              hipStream_t stream) {
    const float* A = (const float*)d_in[0];
    const float* E = (const float*)d_in[1];
    const float* persona = (const float*)d_in[2];
    const float* T = (const float*)d_in[3];
    const float* e = (const float*)d_in[4];
    const float* r = (const float*)d_in[5];
    const float* W = (const float*)d_in[6];
    const int* times = (const int*)d_in[7];
    float* out = (float*)d_out;

    char* ws = (char*)d_ws;
    __hip_bfloat16* Abf = (__hip_bfloat16*)ws;                    // 2 MB
    __hip_bfloat16* Mbf = (__hip_bfloat16*)(ws + (2 << 20));      // 2 MB
    float4* qtab = (float4*)(ws + (4 << 20));                     // 320 KB
    float* cst = (float*)(ws + (4 << 20) + P * N * 16);           // 40 B

    prep_kernel<<<N, 256, 0, stream>>>(E, A, persona, T, e, r, W, times,
                                       Abf, Mbf, qtab, cst);
    const int ntri = 64 * 65 / 2;  // 2080 upper-triangle tiles
    gram_kernel<<<ntri, 256, 0, stream>>>(Abf, Mbf, qtab, cst, out);
}

// Round 4
// 131.223 us; speedup vs baseline: 1.9449x; 1.9449x over previous
//
#include <hip/hip_runtime.h>
#include <hip/hip_bf16.h>

#define N 4096
#define F 256
#define P 5
#define EPSV 1e-8f
#define NSTEP 8          // K-steps of 32 over F=256
#define SWZ(slot, row) ((slot) ^ (((row) >> 1) & 7))

typedef __attribute__((ext_vector_type(8))) short bf16x8;
typedef __attribute__((ext_vector_type(4))) float f32x4;

__device__ __forceinline__ f32x4 mfma16(bf16x8 a, bf16x8 b, f32x4 c) {
    return __builtin_amdgcn_mfma_f32_16x16x32_bf16(a, b, c, 0, 0, 0);
}

__device__ __forceinline__ void gload16(const __hip_bfloat16* src, const char* ldsdst) {
    __builtin_amdgcn_global_load_lds(
        (const __attribute__((address_space(1))) void*)src,
        (__attribute__((address_space(3))) void*)ldsdst, 16, 0, 0);
}

// K0 (fused): msg = E @ A via sparse index compaction, norms, bf16 casts,
// per-(persona,row) float4 table {alpha, beta, p, p+delta}, per-persona consts.
__global__ __launch_bounds__(256, 8) void prep_kernel(
    const float* __restrict__ E, const float* __restrict__ A,
    const float* __restrict__ persona,
    const float* __restrict__ Tt, const float* __restrict__ ee,
    const float* __restrict__ rr, const float* __restrict__ Ww,
    const int* __restrict__ times,
    __hip_bfloat16* __restrict__ Abf, __hip_bfloat16* __restrict__ Mbf,
    float4* __restrict__ qtab, float* __restrict__ cst) {
    __shared__ int cnt;
    __shared__ int list[1024];
    const int a = blockIdx.x;
    const int t = threadIdx.x;
    if (t == 0) cnt = 0;
    __syncthreads();
    const float4* erow = (const float4*)(E + (size_t)a * N);
    for (int b = t; b < N / 4; b += 256) {
        const float4 v = erow[b];
        if (v.x != 0.f) list[atomicAdd(&cnt, 1)] = 4 * b;
        if (v.y != 0.f) list[atomicAdd(&cnt, 1)] = 4 * b + 1;
        if (v.z != 0.f) list[atomicAdd(&cnt, 1)] = 4 * b + 2;
        if (v.w != 0.f) list[atomicAdd(&cnt, 1)] = 4 * b + 3;
    }
    __syncthreads();
    const int c = cnt;
    float s0 = 0.f, s1 = 0.f, s2 = 0.f, s3 = 0.f;
    int j = 0;
    for (; j + 4 <= c; j += 4) {
        s0 += A[(size_t)list[j] * F + t];
        s1 += A[(size_t)list[j + 1] * F + t];
        s2 += A[(size_t)list[j + 2] * F + t];
        s3 += A[(size_t)list[j + 3] * F + t];
    }
    for (; j < c; ++j) s0 += A[(size_t)list[j] * F + t];
    const float mv = (s0 + s1) + (s2 + s3);
    const float av = A[(size_t)a * F + t];
    Abf[(size_t)a * F + t] = __float2bfloat16(av);
    Mbf[(size_t)a * F + t] = __float2bfloat16(mv);

    float paa = av * av, pam = av * mv, pmm = mv * mv;
    #pragma unroll
    for (int o = 32; o > 0; o >>= 1) {
        paa += __shfl_down(paa, o);
        pam += __shfl_down(pam, o);
        pmm += __shfl_down(pmm, o);
    }
    __shared__ float s[3][4];
    const int wid = t >> 6;
    if ((t & 63) == 0) { s[0][wid] = paa; s[1][wid] = pam; s[2][wid] = pmm; }
    __syncthreads();
    if (t < P) {
        const float naa = s[0][0] + s[0][1] + s[0][2] + s[0][3];
        const float nam = s[1][0] + s[1][1] + s[1][2] + s[1][3];
        const float nmm = s[2][0] + s[2][1] + s[2][2] + s[2][3];
        const float Ti = Tt[t], ei = ee[t], ri = rr[t], Wi = Ww[t];
        const float wb = (1.f - ri) * Wi;
        const float n2 = ri * ri * naa + 2.f * ri * wb * nam + wb * wb * nmm;
        const float rn = rsqrtf(n2);
        const float p = persona[(size_t)(*times) * (size_t)N * P + (size_t)a * P + t];
        float4 q;
        q.x = ri * rn;                       // alpha
        q.y = wb * rn;                       // beta
        q.z = p;                             // p0
        q.w = p + (t == 0 ? 1.f : 0.f);      // p1 (i==0 init term)
        qtab[t * N + a] = q;
        if (a == 0) {
            const float invT = 1.f / (Ti + EPSV);
            const float sc = ei / (ei * __expf(invT) + EPSV);
            cst[2 * t] = invT * 1.4426950408889634f;   // k1 (log2 exponent scale)
            cst[2 * t + 1] = __log2f(sc);              // lsc (folded post-scale)
        }
    }
}

// K1: fused 4-Gram MFMA + dual-tile persona epilogue over the upper triangle.
// 64x64 tile, 4 waves (2x2). Col panels staged full-K in LDS (one barrier);
// row fragments loaded directly from global (L2-resident). Barrier-free K-loop.
__global__ __launch_bounds__(256) void gram_kernel(
    const __hip_bfloat16* __restrict__ Abf, const __hip_bfloat16* __restrict__ Mbf,
    const float4* __restrict__ qtab, const float* __restrict__ cst,
    float* __restrict__ out) {
    // colA [64][256] bf16 at 0 (32KB), colM at 32768 (32KB). Reused for transpose.
    __shared__ __align__(16) char smem[65536];

    const int t = threadIdx.x;
    const int lane = t & 63;
    const int w = t >> 6;
    const int wr = w >> 1, wc = w & 1;

    // triangle decode: bid -> (by <= bx)
    int bid = blockIdx.x;
    int bx = (int)((sqrtf(8.f * (float)bid + 1.f) - 1.f) * 0.5f);
    while ((bx + 1) * (bx + 2) / 2 <= bid) ++bx;
    while (bx * (bx + 1) / 2 > bid) --bx;
    const int by = bid - bx * (bx + 1) / 2;
    const int row0 = by << 6, col0 = bx << 6;

    // ---- stage col panels, full K, once. Wave-uniform LDS dest (HW adds lane*16).
    // lane covers row = it*8 + w*2 + (lane>>5), 16B slot = lane&31; source column
    // pre-swizzled with the involution SWZ so LDS stays linear.
    {
        const int srow = (lane >> 5);
        const int sslot = lane & 31;
        #pragma unroll
        for (int it = 0; it < 8; ++it) {
            const int row = it * 8 + w * 2 + srow;
            const size_t goff = (size_t)(col0 + row) * F + SWZ(sslot, row) * 8;
            const char* dst = smem + it * 4096 + w * 1024;
            gload16(Abf + goff, dst);
            gload16(Mbf + goff, dst + 32768);
        }
    }

    const int frow = lane & 15;
    const int fg = lane >> 4;  // 0..3

    // row-fragment global base pointers (per lane)
    const size_t rbase = (size_t)(row0 + wr * 32 + frow) * F + fg * 8;
    const __hip_bfloat16* pA0 = Abf + rbase;
    const __hip_bfloat16* pA1 = pA0 + 16 * F;
    const __hip_bfloat16* pM0 = Mbf + rbase;
    const __hip_bfloat16* pM1 = pM0 + 16 * F;

    f32x4 acc[4][2][2];
    #pragma unroll
    for (int g = 0; g < 4; ++g)
        #pragma unroll
        for (int m = 0; m < 2; ++m)
            #pragma unroll
            for (int n = 0; n < 2; ++n) acc[g][m][n] = (f32x4){0.f, 0.f, 0.f, 0.f};

    bf16x8 rA[2][2], rM[2][2];  // [buf][m]
    rA[0][0] = *(const bf16x8*)(pA0);
    rA[0][1] = *(const bf16x8*)(pA1);
    rM[0][0] = *(const bf16x8*)(pM0);
    rM[0][1] = *(const bf16x8*)(pM1);

    __syncthreads();  // staging complete (compiler drains vmcnt here, once)

    #pragma unroll
    for (int s = 0; s < NSTEP; ++s) {
        const int cb = s & 1, nb = cb ^ 1;
        if (s + 1 < NSTEP) {
            rA[nb][0] = *(const bf16x8*)(pA0 + (s + 1) * 32);
            rA[nb][1] = *(const bf16x8*)(pA1 + (s + 1) * 32);
            rM[nb][0] = *(const bf16x8*)(pM0 + (s + 1) * 32);
            rM[nb][1] = *(const bf16x8*)(pM1 + (s + 1) * 32);
        }
        bf16x8 bA[2], bM[2];
        #pragma unroll
        for (int n = 0; n < 2; ++n) {
            const int crow = wc * 32 + n * 16 + frow;
            const int off = crow * 512 + SWZ(s * 4 + fg, crow) * 16;
            bA[n] = *(const bf16x8*)(smem + off);
            bM[n] = *(const bf16x8*)(smem + 32768 + off);
        }
        #pragma unroll
        for (int m = 0; m < 2; ++m)
            #pragma unroll
            for (int n = 0; n < 2; ++n) {
                acc[0][m][n] = mfma16(rA[cb][m], bA[n], acc[0][m][n]);
                acc[1][m][n] = mfma16(rA[cb][m], bM[n], acc[1][m][n]);
                acc[2][m][n] = mfma16(rM[cb][m], bA[n], acc[2][m][n]);
                acc[3][m][n] = mfma16(rM[cb][m], bM[n], acc[3][m][n]);
            }
    }

    // Epilogue: g symmetric; out(r,c) = sum th*pc0*pr1, out(c,r) = sum th*pr0*pc1
    const int jr = fg << 2;
    float o1[2][2][4], o2[2][2][4];
    #pragma unroll
    for (int m = 0; m < 2; ++m)
        #pragma unroll
        for (int n = 0; n < 2; ++n)
            #pragma unroll
            for (int j = 0; j < 4; ++j) { o1[m][n][j] = 0.f; o2[m][n][j] = 0.f; }

    #pragma unroll
    for (int i = 0; i < P; ++i) {
        const float k1 = cst[2 * i], lsc = cst[2 * i + 1];
        float4 qc[2];
        #pragma unroll
        for (int n = 0; n < 2; ++n)
            qc[n] = qtab[i * N + col0 + wc * 32 + n * 16 + frow];
        #pragma unroll
        for (int m = 0; m < 2; ++m) {
            #pragma unroll
            for (int j = 0; j < 4; ++j) {
                const int gr = row0 + wr * 32 + m * 16 + jr + j;
                const float4 qr = qtab[i * N + gr];
                #pragma unroll
                for (int n = 0; n < 2; ++n) {
                    const float h0 = qr.x * acc[0][m][n][j] + qr.y * acc[2][m][n][j];
                    const float h1 = qr.x * acc[1][m][n][j] + qr.y * acc[3][m][n][j];
                    const float g = h0 * qc[n].x + h1 * qc[n].y;
                    const float x = exp2f(fmaf(g, k1, lsc));
                    const float e2 = exp2f(x * 2.8853900817779268f);  // exp(2x)
                    const float th = 1.f - 2.f * __builtin_amdgcn_rcpf(e2 + 1.f);
                    o1[m][n][j] = fmaf(th * qc[n].z, qr.w, o1[m][n][j]);
                    o2[m][n][j] = fmaf(th * qr.z, qc[n].w, o2[m][n][j]);
                }
            }
        }
    }

    // tile1 (row0, col0): direct stores
    #pragma unroll
    for (int m = 0; m < 2; ++m)
        #pragma unroll
        for (int j = 0; j < 4; ++j) {
            const int gr = row0 + wr * 32 + m * 16 + jr + j;
            #pragma unroll
            for (int n = 0; n < 2; ++n) {
                const int gc = col0 + wc * 32 + n * 16 + frow;
                out[(size_t)gr * N + gc] = o1[m][n][j];
            }
        }

    // all waves done reading col panels before the transpose overwrites LDS
    __syncthreads();

    // tile2 (col0, row0): transpose through LDS (XOR-swizzled f32 [64][64]), float4 stores
    if (by != bx) {
        float* tb = (float*)smem;
        #pragma unroll
        for (int m = 0; m < 2; ++m)
            #pragma unroll
            for (int n = 0; n < 2; ++n) {
                const int lc = wc * 32 + n * 16 + frow;
                #pragma unroll
                for (int j = 0; j < 4; ++j) {
                    const int lr = wr * 32 + m * 16 + jr + j;
                    tb[lc * 64 + (lr ^ ((lc & 15) << 2))] = o2[m][n][j];
                }
            }
        __syncthreads();
        const int trow = t >> 2;
        const int tc4 = (t & 3) << 2;
        #pragma unroll
        for (int k = 0; k < 4; ++k) {
            const int col = (tc4 + k * 16) ^ ((trow & 15) << 2);
            const float4 v = *(const float4*)&tb[trow * 64 + col];
            *(float4*)&out[(size_t)(col0 + trow) * N + row0 + tc4 + k * 16] = v;
        }
    }
}

extern "C" void kernel_launch(void* const* d_in, const int* in_sizes, int n_in,
                              void* d_out, int out_size, void* d_ws, size_t ws_size,
                              hipStream_t stream) {
    const float* A = (const float*)d_in[0];
    const float* E = (const float*)d_in[1];
    const float* persona = (const float*)d_in[2];
    const float* T = (const float*)d_in[3];
    const float* e = (const float*)d_in[4];
    const float* r = (const float*)d_in[5];
    const float* W = (const float*)d_in[6];
    const int* times = (const int*)d_in[7];
    float* out = (float*)d_out;

    char* ws = (char*)d_ws;
    __hip_bfloat16* Abf = (__hip_bfloat16*)ws;                    // 2 MB
    __hip_bfloat16* Mbf = (__hip_bfloat16*)(ws + (2 << 20));      // 2 MB
    float4* qtab = (float4*)(ws + (4 << 20));                     // 320 KB
    float* cst = (float*)(ws + (4 << 20) + P * N * 16);           // 40 B

    prep_kernel<<<N, 256, 0, stream>>>(E, A, persona, T, e, r, W, times,
                                       Abf, Mbf, qtab, cst);
    const int ntri = 64 * 65 / 2;  // 2080 upper-triangle tiles
    gram_kernel<<<ntri, 256, 0, stream>>>(Abf, Mbf, qtab, cst, out);
}